// Round 1
// 1028.489 us; speedup vs baseline: 1.0086x; 1.0086x over previous
//
#include <hip/hip_runtime.h>
#include <hip/hip_bf16.h>

typedef float float4v __attribute__((ext_vector_type(4)));
typedef __bf16 bf16x8 __attribute__((ext_vector_type(8)));

#define MFMA16(a, b, c) __builtin_amdgcn_mfma_f32_16x16x32_bf16(a, b, c, 0, 0, 0)

__device__ __forceinline__ float fsigmoid(float x) {
    return __builtin_amdgcn_rcpf(1.0f + __expf(-x));
}
__device__ __forceinline__ float ftanh_(float x) {
    float e = __expf(2.0f * x);
    return 1.0f - 2.0f * __builtin_amdgcn_rcpf(e + 1.0f);
}
__device__ __forceinline__ float softplusf(float x) {
    return fmaxf(x, 0.0f) + __logf(1.0f + __expf(-fabsf(x)));
}

// ---------------------------------------------------------------------------
// Kernel 1: GRU with compensated bf16 MFMA, restructured into h-phase /
// x-phase. The x.W_ih part of step t+1 (72 MFMAs) is computed during step t,
// in the same barrier-free region as the gate epilogue, so the epilogue VALU
// (sigmoid/tanh, ~500 cy) interleaves with MFMA issue instead of serializing
// after it. x is staged TWO steps ahead into the double buffer (buf[t&1] is
// free for x(t+2) because x(t) fragments were consumed during step t-1).
// ---------------------------------------------------------------------------
#define STAGE(U0, U1, XHd, XLd) {                                              \
    bf16x8 fh, fl;                                                             \
    _Pragma("unroll")                                                          \
    for (int j = 0; j < 4; ++j) {                                              \
        __bf16 h0 = (__bf16)(U0)[j]; fh[j] = h0;                               \
        fl[j] = (__bf16)((U0)[j] - (float)h0);                                 \
        __bf16 h1 = (__bf16)(U1)[j]; fh[j + 4] = h1;                           \
        fl[j + 4] = (__bf16)((U1)[j] - (float)h1);                             \
    }                                                                          \
    *(bf16x8*)&(XHd)[tid * 8] = fh;                                            \
    *(bf16x8*)&(XLd)[tid * 8] = fl;                                            \
}

#define X_PHASE(XHp, XLp)                                                      \
    _Pragma("unroll")                                                          \
    for (int c = 0; c < 4; ++c) {                                              \
        const int fo_ = (c * 64 + lane) * 8;                                   \
        bf16x8 xh = *(const bf16x8*)&(XHp)[fo_];                               \
        bf16x8 xl = *(const bf16x8*)&(XLp)[fo_];                               \
        _Pragma("unroll")                                                      \
        for (int ct = 0; ct < 2; ++ct) {                                       \
            nR[ct]  = MFMA16(xh, wihh[0][ct][c], nR[ct]);                      \
            nR[ct]  = MFMA16(xl, wihh[0][ct][c], nR[ct]);                      \
            nR[ct]  = MFMA16(xh, wihl[0][ct][c], nR[ct]);                      \
            nZ[ct]  = MFMA16(xh, wihh[1][ct][c], nZ[ct]);                      \
            nZ[ct]  = MFMA16(xl, wihh[1][ct][c], nZ[ct]);                      \
            nZ[ct]  = MFMA16(xh, wihl[1][ct][c], nZ[ct]);                      \
            nIN[ct] = MFMA16(xh, wihh[2][ct][c], nIN[ct]);                     \
            nIN[ct] = MFMA16(xl, wihh[2][ct][c], nIN[ct]);                     \
            nIN[ct] = MFMA16(xh, wihl[2][ct][c], nIN[ct]);                     \
        }                                                                      \
    }

#define NEXT_INIT()                                                            \
    _Pragma("unroll")                                                          \
    for (int ct = 0; ct < 2; ++ct) {                                           \
        nR[ct]  = (float4v){biasR[ct],  biasR[ct],  biasR[ct],  biasR[ct]};    \
        nZ[ct]  = (float4v){biasZ[ct],  biasZ[ct],  biasZ[ct],  biasZ[ct]};    \
        nIN[ct] = (float4v){biasIN[ct], biasIN[ct], biasIN[ct], biasIN[ct]};   \
    }

__global__ __launch_bounds__(256, 1)
void gru_kernel(const float* __restrict__ friend_x,
                const float* __restrict__ W_ih, const float* __restrict__ W_hh,
                const float* __restrict__ b_ih, const float* __restrict__ b_hh,
                const int* __restrict__ fmask,
                float* __restrict__ friend_out)
{
    __shared__ __align__(16) __bf16 lds[8 * 2048];
    __shared__ int s_lf[16];
    __shared__ int s_n[16];

    const int tid = threadIdx.x;
    const int wv = tid >> 6;
    const int lane = tid & 63;
    const int cn = lane & 15;
    const int qq = lane >> 4;

    __bf16* const XH0 = lds;
    __bf16* const XH1 = lds + 2048;
    __bf16* const XL0 = lds + 2 * 2048;
    __bf16* const XL1 = lds + 3 * 2048;
    __bf16* const HH0 = lds + 4 * 2048;
    __bf16* const HH1 = lds + 5 * 2048;
    __bf16* const HL0 = lds + 6 * 2048;
    __bf16* const HL1 = lds + 7 * 2048;

    if (tid < 16) {
        const int p = blockIdx.x * 16 + tid;
        const int v = p / 68;
        const int j = p - v * 68;
        const int n = (63 - v) + 64 * j;
        s_n[tid] = n;
        const int* mp = fmask + (long)n * 64;
        int s = 0;
        for (int i = 0; i < 64; ++i) s += mp[i];
        s_lf[tid] = s;
    }

    {
        bf16x8 z8;
#pragma unroll
        for (int j = 0; j < 8; ++j) z8[j] = (__bf16)0.0f;
        for (int i = tid; i < 4 * 2048 / 8; i += 256) ((bf16x8*)HH0)[i] = z8;
    }

    // ---- weights -> registers as B-frags, hi/lo compensated ----
    bf16x8 wihh[3][2][4], wihl[3][2][4], whhh[3][2][4], whhl[3][2][4];
#pragma unroll
    for (int gate = 0; gate < 3; ++gate)
#pragma unroll
        for (int ct = 0; ct < 2; ++ct) {
            const int row = gate * 128 + wv * 32 + ct * 16 + cn;
#pragma unroll
            for (int c = 0; c < 4; ++c) {
                const float* p = W_ih + row * 128 + c * 32 + qq * 8;
                float4v u0 = *(const float4v*)p;
                float4v u1 = *(const float4v*)(p + 4);
                bf16x8 fh, fl;
#pragma unroll
                for (int j = 0; j < 4; ++j) {
                    __bf16 h0 = (__bf16)u0[j]; fh[j] = h0; fl[j] = (__bf16)(u0[j] - (float)h0);
                    __bf16 h1 = (__bf16)u1[j]; fh[j + 4] = h1; fl[j + 4] = (__bf16)(u1[j] - (float)h1);
                }
                wihh[gate][ct][c] = fh; wihl[gate][ct][c] = fl;
                const float* q = W_hh + row * 128 + c * 32 + qq * 8;
                float4v v0 = *(const float4v*)q;
                float4v v1 = *(const float4v*)(q + 4);
                bf16x8 gh, gl;
#pragma unroll
                for (int j = 0; j < 4; ++j) {
                    __bf16 h0 = (__bf16)v0[j]; gh[j] = h0; gl[j] = (__bf16)(v0[j] - (float)h0);
                    __bf16 h1 = (__bf16)v1[j]; gh[j + 4] = h1; gl[j + 4] = (__bf16)(v1[j] - (float)h1);
                }
                whhh[gate][ct][c] = gh; whhl[gate][ct][c] = gl;
            }
        }

    float biasR[2], biasZ[2], biasIN[2], biasHN[2];
#pragma unroll
    for (int ct = 0; ct < 2; ++ct) {
        const int cc = wv * 32 + ct * 16 + cn;
        biasR[ct] = b_ih[cc] + b_hh[cc];
        biasZ[ct] = b_ih[128 + cc] + b_hh[128 + cc];
        biasIN[ct] = b_ih[256 + cc];
        biasHN[ct] = b_hh[256 + cc];
    }

    __syncthreads();   // s_n/s_lf + h zeros visible

    const int srow = lane & 15;
    const int ss = lane >> 4;
    const float* xp = friend_x + (long)s_n[srow] * 8192 + wv * 32 + ss * 8;

    int lfA[4], nA[4];
#pragma unroll
    for (int r = 0; r < 4; ++r) { lfA[r] = s_lf[qq * 4 + r]; nA[r] = s_n[qq * 4 + r]; }
    int maxlf = 0;
    for (int i = 0; i < 16; ++i) maxlf = (s_lf[i] > maxlf) ? s_lf[i] : maxlf;

    // stage x(0) and x(1); rows past lf read valid-but-unused data (LF=64)
    {
        float4v a0 = *(const float4v*)(xp);
        float4v a1 = *(const float4v*)(xp + 4);
        float4v b0 = *(const float4v*)(xp + 128);
        float4v b1 = *(const float4v*)(xp + 132);
        STAGE(a0, a1, XH0, XL0);
        STAGE(b0, b1, XH1, XL1);
    }
    __syncthreads();

    // precompute x-part accumulators for t = 0
    float4v nR[2], nZ[2], nIN[2];
    NEXT_INIT();
    X_PHASE(XH0, XL0);
    __syncthreads();   // buf0 reads done before t=0 commits x(2) into buf0

    float hC[2][4];
#pragma unroll
    for (int ct = 0; ct < 2; ++ct)
#pragma unroll
        for (int r = 0; r < 4; ++r) hC[ct][r] = 0.0f;

    for (int t = 0; t < maxlf; ++t) {
        const int cur = t & 1;
        __bf16* const HHc = cur ? HH1 : HH0;   // h(t)
        __bf16* const HLc = cur ? HL1 : HL0;
        __bf16* const XHr = cur ? XH0 : XH1;   // x(t+1)
        __bf16* const XLr = cur ? XL0 : XL1;
        __bf16* const XHw = cur ? XH1 : XH0;   // dest for x(t+2)
        __bf16* const XLw = cur ? XL1 : XL0;
        __bf16* const HHn = cur ? HH0 : HH1;   // h(t+1)
        __bf16* const HLn = cur ? HL0 : HL1;

        const bool pf2 = (t + 2 < maxlf);
        float4v u0, u1;
        if (pf2) {   // prefetch x(t+2) early; latency covered by both phases
            u0 = *(const float4v*)(xp + (t + 2) * 128);
            u1 = *(const float4v*)(xp + (t + 2) * 128 + 4);
        }

        // current-step accumulators = precomputed x-part (+ bias)
        float4v aR[2], aZ[2], aIN[2], aHN[2];
#pragma unroll
        for (int ct = 0; ct < 2; ++ct) {
            aR[ct] = nR[ct]; aZ[ct] = nZ[ct]; aIN[ct] = nIN[ct];
            aHN[ct] = (float4v){biasHN[ct], biasHN[ct], biasHN[ct], biasHN[ct]};
        }

        // ---- h-phase: 72 MFMAs, h(t).W_hh (compensated) ----
#pragma unroll
        for (int c = 0; c < 4; ++c) {
            const int fo_ = (c * 64 + lane) * 8;
            bf16x8 hh = *(const bf16x8*)&HHc[fo_];
            bf16x8 hl = *(const bf16x8*)&HLc[fo_];
#pragma unroll
            for (int ct = 0; ct < 2; ++ct) {
                aR[ct]  = MFMA16(hh, whhh[0][ct][c], aR[ct]);
                aR[ct]  = MFMA16(hl, whhh[0][ct][c], aR[ct]);
                aR[ct]  = MFMA16(hh, whhl[0][ct][c], aR[ct]);
                aZ[ct]  = MFMA16(hh, whhh[1][ct][c], aZ[ct]);
                aZ[ct]  = MFMA16(hl, whhh[1][ct][c], aZ[ct]);
                aZ[ct]  = MFMA16(hh, whhl[1][ct][c], aZ[ct]);
                aHN[ct] = MFMA16(hh, whhh[2][ct][c], aHN[ct]);
                aHN[ct] = MFMA16(hl, whhh[2][ct][c], aHN[ct]);
                aHN[ct] = MFMA16(hh, whhl[2][ct][c], aHN[ct]);
            }
        }

        // ---- x-phase for t+1: 72 MFMAs, register-independent of the
        //      epilogue below -> scheduler interleaves MFMA issue with the
        //      epilogue's VALU (sigmoid/tanh), hiding one under the other ----
        const bool hasNext = (t + 1 < maxlf);
        if (hasNext) {
            NEXT_INIT();
            X_PHASE(XHr, XLr);
        }

        // commit prefetched x(t+2) (buf[t&1] free since step t-1's reads)
        if (pf2) {
            STAGE(u0, u1, XHw, XLw);
        }

        // ---- epilogue: gates (fp32) + h update + write h hi/lo ----
#pragma unroll
        for (int ct = 0; ct < 2; ++ct) {
            const int col = wv * 32 + ct * 16 + cn;
            const int c2 = col >> 5, s2 = (col >> 3) & 3, j2 = col & 7;
#pragma unroll
            for (int reg = 0; reg < 4; ++reg) {
                const int row = qq * 4 + reg;
                float r = fsigmoid(aR[ct][reg]);
                float z = fsigmoid(aZ[ct][reg]);
                float nn = ftanh_(aIN[ct][reg] + r * aHN[ct][reg]);
                float h = (1.0f - z) * nn + z * hC[ct][reg];
                hC[ct][reg] = h;
                __bf16 hhi = (__bf16)h;
                __bf16 hlo = (__bf16)(h - (float)hhi);
                const int sl = (c2 * 64 + row + 16 * s2) * 8 + j2;
                HHn[sl] = hhi;
                HLn[sl] = hlo;
                if (t + 1 == lfA[reg])
                    friend_out[(long)nA[reg] * 128 + col] = h;
            }
        }

        __syncthreads();
    }
}

// ---------------------------------------------------------------------------
// Kernel 2: per-sequence attention. score[l] = common_x[n,l,:].v where
// v = (cat @ W_friend^T) @ W_beta. Streams common_x only for l < lc.
// Streaming loop unrolled x4 so each 32-lane group keeps 4 independent
// 512B row loads in flight instead of serializing on the shfl-reduce chain.
// ---------------------------------------------------------------------------
__global__ __launch_bounds__(256)
void attn_kernel(const float* __restrict__ self_x,
                 const float* __restrict__ common_x,
                 const float* __restrict__ common_time,
                 const float* __restrict__ W_friend,
                 const float* __restrict__ W_beta,
                 const int* __restrict__ csm,
                 const int* __restrict__ user_idx,
                 const float* __restrict__ friend_out,
                 float* __restrict__ tf)
{
    const int n = blockIdx.x;
    const int tid = threadIdx.x;
    const int wv = tid >> 6, lane = tid & 63;
    __shared__ __align__(16) float catf[256];
    __shared__ float sfs[128];
    __shared__ __align__(16) float vv[128];
    __shared__ float vpart[2][128];
    __shared__ int lcp[4];
    __shared__ int s_lc;
    __shared__ float wsum[4];

    if (tid < 128) catf[tid] = self_x[user_idx[n] * 128 + tid];
    else           catf[tid] = friend_out[(long)n * 128 + tid - 128];

    int mv = csm[(long)n * 256 + tid];
#pragma unroll
    for (int o = 32; o; o >>= 1) mv += __shfl_down(mv, o);
    if (lane == 0) lcp[wv] = mv;
    __syncthreads();
    if (tid == 0) s_lc = lcp[0] + lcp[1] + lcp[2] + lcp[3];

    // sf[h] = W_friend[h,:] . cat
    float4v c4 = *(const float4v*)&catf[4 * lane];
    for (int i = 0; i < 32; ++i) {
        const int h = wv * 32 + i;
        float4v w4 = *(const float4v*)(W_friend + h * 256 + 4 * lane);
        float p = w4[0] * c4[0] + w4[1] * c4[1] + w4[2] * c4[2] + w4[3] * c4[3];
#pragma unroll
        for (int o = 1; o < 64; o <<= 1) p += __shfl_xor(p, o);
        if (lane == 0) sfs[h] = p;
    }
    __syncthreads();

    // v[col] = sum_h sf[h] * W_beta[h, col]
    {
        const int col = tid & 127, half = tid >> 7;
        float acc = 0.f;
#pragma unroll 4
        for (int kk = 0; kk < 64; ++kk) {
            const int hh = kk * 2 + half;
            acc += sfs[hh] * W_beta[hh * 128 + col];
        }
        vpart[half][col] = acc;
    }
    __syncthreads();
    if (tid < 128) vv[tid] = vpart[0][tid] + vpart[1][tid];
    __syncthreads();

    const int lc = s_lc;
    const int lh = lane & 31, sub = lane >> 5;
    float4v v4 = *(const float4v*)&vv[4 * lh];
    const float* cxn = common_x + (long)n * 32768 + 4 * lh;
    const float* ctn = common_time + (long)n * 256;
    float acc = 0.f;
#pragma unroll 4
    for (int l0 = wv * 2 + sub; l0 < lc; l0 += 8) {
        float4v x4 = *(const float4v*)(cxn + l0 * 128);
        float p = x4[0] * v4[0] + x4[1] * v4[1] + x4[2] * v4[2] + x4[3] * v4[3];
#pragma unroll
        for (int o = 1; o < 32; o <<= 1) p += __shfl_xor(p, o);
        float contrib = softplusf(p) * __expf(1.0f - ctn[l0] * 1e-6f);
        if (lh == 0) acc += contrib;
    }
    acc += __shfl_xor(acc, 32);
    if (lane == 0) wsum[wv] = acc;
    __syncthreads();
    if (tid == 0) tf[n] = wsum[0] + wsum[1] + wsum[2] + wsum[3];
}

// ---------------------------------------------------------------------------
// Kernel 3: group softmax (over padded zeros, faithful) + weighted sum.
// ---------------------------------------------------------------------------
__global__ __launch_bounds__(128)
void agg_kernel(const float* __restrict__ tf, const float* __restrict__ fo,
                const int* __restrict__ gather_idx, const int* __restrict__ pad_mask,
                float* __restrict__ out)
{
    const int b = blockIdx.x, tid = threadIdx.x;
    __shared__ float tfp[16];
    __shared__ int gidx[16];
    __shared__ float pmf[16];
    if (tid < 16) {
        const int gg = gather_idx[b * 16 + tid];
        const int pp = pad_mask[b * 16 + tid];
        gidx[tid] = gg; pmf[tid] = (float)pp;
        tfp[tid] = pp ? tf[gg] : 0.0f;
    }
    __syncthreads();
    float m = tfp[0];
#pragma unroll
    for (int f = 1; f < 16; ++f) m = fmaxf(m, tfp[f]);
    float e[16]; float s = 0.f;
#pragma unroll
    for (int f = 0; f < 16; ++f) { e[f] = __expf(tfp[f] - m); s += e[f]; }
    const float inv = 1.0f / s;
    float acc = 0.f;
#pragma unroll
    for (int f = 0; f < 16; ++f) {
        if (pmf[f] != 0.0f) {
            const float w = e[f] * inv;
            acc += w * fo[(long)gidx[f] * 128 + tid];
        }
    }
    out[b * 128 + tid] = acc;
}

extern "C" void kernel_launch(void* const* d_in, const int* in_sizes, int n_in,
                              void* d_out, int out_size, void* d_ws, size_t ws_size,
                              hipStream_t stream)
{
    const float* self_x      = (const float*)d_in[0];
    const float* common_x    = (const float*)d_in[1];
    const float* common_time = (const float*)d_in[2];
    const float* friend_x    = (const float*)d_in[3];
    const float* W_ih        = (const float*)d_in[4];
    const float* W_hh        = (const float*)d_in[5];
    const float* b_ih        = (const float*)d_in[6];
    const float* b_hh        = (const float*)d_in[7];
    const float* W_friend    = (const float*)d_in[8];
    const float* W_beta      = (const float*)d_in[9];
    const int* fmask         = (const int*)d_in[10];
    const int* csm           = (const int*)d_in[11];
    const int* uidx          = (const int*)d_in[12];
    const int* gidx          = (const int*)d_in[13];
    const int* pmask         = (const int*)d_in[14];
    float* out = (float*)d_out;

    const int N = in_sizes[12];          // 4352
    const int B = in_sizes[0] / 128;     // 512

    float* fo_ws = (float*)d_ws;                       // [N,128] fp32
    float* tf_ws = fo_ws + (size_t)N * 128;            // [N] fp32

    gru_kernel<<<(N + 15) / 16, 256, 0, stream>>>(friend_x, W_ih, W_hh, b_ih, b_hh,
                                                  fmask, fo_ws);
    attn_kernel<<<N, 256, 0, stream>>>(self_x, common_x, common_time,
                                       W_friend, W_beta, csm, uidx, fo_ws, tf_ws);
    agg_kernel<<<B, 128, 0, stream>>>(tf_ws, fo_ws, gidx, pmask, out);

    (void)n_in; (void)out_size; (void)ws_size;
}

// Round 3
// 995.648 us; speedup vs baseline: 1.0419x; 1.0330x over previous
//
#include <hip/hip_runtime.h>
#include <hip/hip_bf16.h>

typedef float float4v __attribute__((ext_vector_type(4)));
typedef __bf16 bf16x8 __attribute__((ext_vector_type(8)));

#define MFMA16(a, b, c) __builtin_amdgcn_mfma_f32_16x16x32_bf16(a, b, c, 0, 0, 0)

__device__ __forceinline__ float fsigmoid(float x) {
    return __builtin_amdgcn_rcpf(1.0f + __expf(-x));
}
__device__ __forceinline__ float ftanh_(float x) {
    float e = __expf(2.0f * x);
    return 1.0f - 2.0f * __builtin_amdgcn_rcpf(e + 1.0f);
}
__device__ __forceinline__ float softplusf(float x) {
    return fmaxf(x, 0.0f) + __logf(1.0f + __expf(-fabsf(x)));
}

// ---------------------------------------------------------------------------
// Kernel 1: GRU with compensated bf16 MFMA, h-phase / x-phase split
// (unchanged).
// ---------------------------------------------------------------------------
#define STAGE(U0, U1, XHd, XLd) {                                              \
    bf16x8 fh, fl;                                                             \
    _Pragma("unroll")                                                          \
    for (int j = 0; j < 4; ++j) {                                              \
        __bf16 h0 = (__bf16)(U0)[j]; fh[j] = h0;                               \
        fl[j] = (__bf16)((U0)[j] - (float)h0);                                 \
        __bf16 h1 = (__bf16)(U1)[j]; fh[j + 4] = h1;                           \
        fl[j + 4] = (__bf16)((U1)[j] - (float)h1);                             \
    }                                                                          \
    *(bf16x8*)&(XHd)[tid * 8] = fh;                                            \
    *(bf16x8*)&(XLd)[tid * 8] = fl;                                            \
}

#define X_PHASE(XHp, XLp)                                                      \
    _Pragma("unroll")                                                          \
    for (int c = 0; c < 4; ++c) {                                              \
        const int fo_ = (c * 64 + lane) * 8;                                   \
        bf16x8 xh = *(const bf16x8*)&(XHp)[fo_];                               \
        bf16x8 xl = *(const bf16x8*)&(XLp)[fo_];                               \
        _Pragma("unroll")                                                      \
        for (int ct = 0; ct < 2; ++ct) {                                       \
            nR[ct]  = MFMA16(xh, wihh[0][ct][c], nR[ct]);                      \
            nR[ct]  = MFMA16(xl, wihh[0][ct][c], nR[ct]);                      \
            nR[ct]  = MFMA16(xh, wihl[0][ct][c], nR[ct]);                      \
            nZ[ct]  = MFMA16(xh, wihh[1][ct][c], nZ[ct]);                      \
            nZ[ct]  = MFMA16(xl, wihh[1][ct][c], nZ[ct]);                      \
            nZ[ct]  = MFMA16(xh, wihl[1][ct][c], nZ[ct]);                      \
            nIN[ct] = MFMA16(xh, wihh[2][ct][c], nIN[ct]);                     \
            nIN[ct] = MFMA16(xl, wihh[2][ct][c], nIN[ct]);                     \
            nIN[ct] = MFMA16(xh, wihl[2][ct][c], nIN[ct]);                     \
        }                                                                      \
    }

#define NEXT_INIT()                                                            \
    _Pragma("unroll")                                                          \
    for (int ct = 0; ct < 2; ++ct) {                                           \
        nR[ct]  = (float4v){biasR[ct],  biasR[ct],  biasR[ct],  biasR[ct]};    \
        nZ[ct]  = (float4v){biasZ[ct],  biasZ[ct],  biasZ[ct],  biasZ[ct]};    \
        nIN[ct] = (float4v){biasIN[ct], biasIN[ct], biasIN[ct], biasIN[ct]};   \
    }

__global__ __launch_bounds__(256, 1)
void gru_kernel(const float* __restrict__ friend_x,
                const float* __restrict__ W_ih, const float* __restrict__ W_hh,
                const float* __restrict__ b_ih, const float* __restrict__ b_hh,
                const int* __restrict__ fmask,
                float* __restrict__ friend_out)
{
    __shared__ __align__(16) __bf16 lds[8 * 2048];
    __shared__ int s_lf[16];
    __shared__ int s_n[16];

    const int tid = threadIdx.x;
    const int wv = tid >> 6;
    const int lane = tid & 63;
    const int cn = lane & 15;
    const int qq = lane >> 4;

    __bf16* const XH0 = lds;
    __bf16* const XH1 = lds + 2048;
    __bf16* const XL0 = lds + 2 * 2048;
    __bf16* const XL1 = lds + 3 * 2048;
    __bf16* const HH0 = lds + 4 * 2048;
    __bf16* const HH1 = lds + 5 * 2048;
    __bf16* const HL0 = lds + 6 * 2048;
    __bf16* const HL1 = lds + 7 * 2048;

    if (tid < 16) {
        const int p = blockIdx.x * 16 + tid;
        const int v = p / 68;
        const int j = p - v * 68;
        const int n = (63 - v) + 64 * j;
        s_n[tid] = n;
        const int* mp = fmask + (long)n * 64;
        int s = 0;
        for (int i = 0; i < 64; ++i) s += mp[i];
        s_lf[tid] = s;
    }

    {
        bf16x8 z8;
#pragma unroll
        for (int j = 0; j < 8; ++j) z8[j] = (__bf16)0.0f;
        for (int i = tid; i < 4 * 2048 / 8; i += 256) ((bf16x8*)HH0)[i] = z8;
    }

    // ---- weights -> registers as B-frags, hi/lo compensated ----
    bf16x8 wihh[3][2][4], wihl[3][2][4], whhh[3][2][4], whhl[3][2][4];
#pragma unroll
    for (int gate = 0; gate < 3; ++gate)
#pragma unroll
        for (int ct = 0; ct < 2; ++ct) {
            const int row = gate * 128 + wv * 32 + ct * 16 + cn;
#pragma unroll
            for (int c = 0; c < 4; ++c) {
                const float* p = W_ih + row * 128 + c * 32 + qq * 8;
                float4v u0 = *(const float4v*)p;
                float4v u1 = *(const float4v*)(p + 4);
                bf16x8 fh, fl;
#pragma unroll
                for (int j = 0; j < 4; ++j) {
                    __bf16 h0 = (__bf16)u0[j]; fh[j] = h0; fl[j] = (__bf16)(u0[j] - (float)h0);
                    __bf16 h1 = (__bf16)u1[j]; fh[j + 4] = h1; fl[j + 4] = (__bf16)(u1[j] - (float)h1);
                }
                wihh[gate][ct][c] = fh; wihl[gate][ct][c] = fl;
                const float* q = W_hh + row * 128 + c * 32 + qq * 8;
                float4v v0 = *(const float4v*)q;
                float4v v1 = *(const float4v*)(q + 4);
                bf16x8 gh, gl;
#pragma unroll
                for (int j = 0; j < 4; ++j) {
                    __bf16 h0 = (__bf16)v0[j]; gh[j] = h0; gl[j] = (__bf16)(v0[j] - (float)h0);
                    __bf16 h1 = (__bf16)v1[j]; gh[j + 4] = h1; gl[j + 4] = (__bf16)(v1[j] - (float)h1);
                }
                whhh[gate][ct][c] = gh; whhl[gate][ct][c] = gl;
            }
        }

    float biasR[2], biasZ[2], biasIN[2], biasHN[2];
#pragma unroll
    for (int ct = 0; ct < 2; ++ct) {
        const int cc = wv * 32 + ct * 16 + cn;
        biasR[ct] = b_ih[cc] + b_hh[cc];
        biasZ[ct] = b_ih[128 + cc] + b_hh[128 + cc];
        biasIN[ct] = b_ih[256 + cc];
        biasHN[ct] = b_hh[256 + cc];
    }

    __syncthreads();

    const int srow = lane & 15;
    const int ss = lane >> 4;
    const float* xp = friend_x + (long)s_n[srow] * 8192 + wv * 32 + ss * 8;

    int lfA[4], nA[4];
#pragma unroll
    for (int r = 0; r < 4; ++r) { lfA[r] = s_lf[qq * 4 + r]; nA[r] = s_n[qq * 4 + r]; }
    int maxlf = 0;
    for (int i = 0; i < 16; ++i) maxlf = (s_lf[i] > maxlf) ? s_lf[i] : maxlf;

    {
        float4v a0 = *(const float4v*)(xp);
        float4v a1 = *(const float4v*)(xp + 4);
        float4v b0 = *(const float4v*)(xp + 128);
        float4v b1 = *(const float4v*)(xp + 132);
        STAGE(a0, a1, XH0, XL0);
        STAGE(b0, b1, XH1, XL1);
    }
    __syncthreads();

    float4v nR[2], nZ[2], nIN[2];
    NEXT_INIT();
    X_PHASE(XH0, XL0);
    __syncthreads();

    float hC[2][4];
#pragma unroll
    for (int ct = 0; ct < 2; ++ct)
#pragma unroll
        for (int r = 0; r < 4; ++r) hC[ct][r] = 0.0f;

    for (int t = 0; t < maxlf; ++t) {
        const int cur = t & 1;
        __bf16* const HHc = cur ? HH1 : HH0;
        __bf16* const HLc = cur ? HL1 : HL0;
        __bf16* const XHr = cur ? XH0 : XH1;
        __bf16* const XLr = cur ? XL0 : XL1;
        __bf16* const XHw = cur ? XH1 : XH0;
        __bf16* const XLw = cur ? XL1 : XL0;
        __bf16* const HHn = cur ? HH0 : HH1;
        __bf16* const HLn = cur ? HL0 : HL1;

        const bool pf2 = (t + 2 < maxlf);
        float4v u0, u1;
        if (pf2) {
            u0 = *(const float4v*)(xp + (t + 2) * 128);
            u1 = *(const float4v*)(xp + (t + 2) * 128 + 4);
        }

        float4v aR[2], aZ[2], aIN[2], aHN[2];
#pragma unroll
        for (int ct = 0; ct < 2; ++ct) {
            aR[ct] = nR[ct]; aZ[ct] = nZ[ct]; aIN[ct] = nIN[ct];
            aHN[ct] = (float4v){biasHN[ct], biasHN[ct], biasHN[ct], biasHN[ct]};
        }

#pragma unroll
        for (int c = 0; c < 4; ++c) {
            const int fo_ = (c * 64 + lane) * 8;
            bf16x8 hh = *(const bf16x8*)&HHc[fo_];
            bf16x8 hl = *(const bf16x8*)&HLc[fo_];
#pragma unroll
            for (int ct = 0; ct < 2; ++ct) {
                aR[ct]  = MFMA16(hh, whhh[0][ct][c], aR[ct]);
                aR[ct]  = MFMA16(hl, whhh[0][ct][c], aR[ct]);
                aR[ct]  = MFMA16(hh, whhl[0][ct][c], aR[ct]);
                aZ[ct]  = MFMA16(hh, whhh[1][ct][c], aZ[ct]);
                aZ[ct]  = MFMA16(hl, whhh[1][ct][c], aZ[ct]);
                aZ[ct]  = MFMA16(hh, whhl[1][ct][c], aZ[ct]);
                aHN[ct] = MFMA16(hh, whhh[2][ct][c], aHN[ct]);
                aHN[ct] = MFMA16(hl, whhh[2][ct][c], aHN[ct]);
                aHN[ct] = MFMA16(hh, whhl[2][ct][c], aHN[ct]);
            }
        }

        const bool hasNext = (t + 1 < maxlf);
        if (hasNext) {
            NEXT_INIT();
            X_PHASE(XHr, XLr);
        }

        if (pf2) {
            STAGE(u0, u1, XHw, XLw);
        }

#pragma unroll
        for (int ct = 0; ct < 2; ++ct) {
            const int col = wv * 32 + ct * 16 + cn;
            const int c2 = col >> 5, s2 = (col >> 3) & 3, j2 = col & 7;
#pragma unroll
            for (int reg = 0; reg < 4; ++reg) {
                const int row = qq * 4 + reg;
                float r = fsigmoid(aR[ct][reg]);
                float z = fsigmoid(aZ[ct][reg]);
                float nn = ftanh_(aIN[ct][reg] + r * aHN[ct][reg]);
                float h = (1.0f - z) * nn + z * hC[ct][reg];
                hC[ct][reg] = h;
                __bf16 hhi = (__bf16)h;
                __bf16 hlo = (__bf16)(h - (float)hhi);
                const int sl = (c2 * 64 + row + 16 * s2) * 8 + j2;
                HHn[sl] = hhi;
                HLn[sl] = hlo;
                if (t + 1 == lfA[reg])
                    friend_out[(long)nA[reg] * 128 + col] = h;
            }
        }

        __syncthreads();
    }
}

// ---------------------------------------------------------------------------
// Kernel 2: proj — v[n,:] = W_beta^T (W_friend . cat_n) for ALL n once,
// instead of per-attn-block. Triple-split bf16 MFMA (hi/mid/lo, 6 products)
// => error ~2^-27 |x||w| ~= fp32-equivalent on the score path.
// 16 rows/block, same fragment layout as the GRU. 272 blocks.
// ---------------------------------------------------------------------------
__device__ __forceinline__ void tsplit8(const float4v u0, const float4v u1,
                                        bf16x8& fh, bf16x8& fm, bf16x8& fl)
{
#pragma unroll
    for (int j = 0; j < 4; ++j) {
        float x0 = u0[j];
        __bf16 h0 = (__bf16)x0; float r0 = x0 - (float)h0;
        __bf16 m0 = (__bf16)r0; float s0 = r0 - (float)m0;
        fh[j] = h0; fm[j] = m0; fl[j] = (__bf16)s0;
        float x1 = u1[j];
        __bf16 h1 = (__bf16)x1; float r1 = x1 - (float)h1;
        __bf16 m1 = (__bf16)r1; float s1 = r1 - (float)m1;
        fh[j + 4] = h1; fm[j + 4] = m1; fl[j + 4] = (__bf16)s1;
    }
}

__global__ __launch_bounds__(256, 1)
void proj_kernel(const float* __restrict__ self_x,
                 const float* __restrict__ friend_out,
                 const float* __restrict__ W_friend,
                 const float* __restrict__ W_beta,
                 const int* __restrict__ user_idx,
                 float* __restrict__ vws)
{
    __shared__ __align__(16) __bf16 catH[4096], catM[4096], catL[4096];
    __shared__ __align__(16) __bf16 sfH[2048], sfM[2048], sfL[2048];

    const int tid = threadIdx.x;
    const int wv = tid >> 6;
    const int lane = tid & 63;
    const int cn = lane & 15;
    const int qq = lane >> 4;
    const int n0 = blockIdx.x * 16;

    // ---- stage cat (slot-linear, same layout as GRU x staging) ----
    {
        const int srow = lane & 15;
        const int ss = lane >> 4;
        const int n_r = n0 + srow;
        const int k = wv * 32 + ss * 8;   // k < 128: self part (chunk c = wv)
        const float* ps = self_x + (long)user_idx[n_r] * 128 + k;
        float4v a0 = *(const float4v*)ps;
        float4v a1 = *(const float4v*)(ps + 4);
        bf16x8 fh, fm, fl;
        tsplit8(a0, a1, fh, fm, fl);
        *(bf16x8*)&catH[tid * 8] = fh;
        *(bf16x8*)&catM[tid * 8] = fm;
        *(bf16x8*)&catL[tid * 8] = fl;
        // k+128: friend part (chunk c = wv+4), slot = tid + 256
        const float* pf = friend_out + (long)n_r * 128 + k;
        float4v b0 = *(const float4v*)pf;
        float4v b1 = *(const float4v*)(pf + 4);
        tsplit8(b0, b1, fh, fm, fl);
        *(bf16x8*)&catH[(tid + 256) * 8] = fh;
        *(bf16x8*)&catM[(tid + 256) * 8] = fm;
        *(bf16x8*)&catL[(tid + 256) * 8] = fl;
    }

    // ---- W_friend B-frags (N-col = wv*32+ct*16+cn, K = 256 -> 8 chunks) ----
    bf16x8 wfh[2][8], wfm[2][8], wfl[2][8];
#pragma unroll
    for (int ct = 0; ct < 2; ++ct) {
        const int hcol = wv * 32 + ct * 16 + cn;
#pragma unroll
        for (int c = 0; c < 8; ++c) {
            const float* p = W_friend + hcol * 256 + c * 32 + qq * 8;
            float4v u0 = *(const float4v*)p;
            float4v u1 = *(const float4v*)(p + 4);
            tsplit8(u0, u1, wfh[ct][c], wfm[ct][c], wfl[ct][c]);
        }
    }

    // ---- W_beta B-frags: B[k=h][col] = W_beta[h*128+col], K=128 -> 4 chunks ----
    bf16x8 wbh[2][4], wbm[2][4], wbl[2][4];
#pragma unroll
    for (int ct = 0; ct < 2; ++ct) {
        const int colN = wv * 32 + ct * 16 + cn;
#pragma unroll
        for (int c = 0; c < 4; ++c) {
            float4v u0, u1;
#pragma unroll
            for (int j = 0; j < 4; ++j) {
                u0[j] = W_beta[(c * 32 + qq * 8 + j) * 128 + colN];
                u1[j] = W_beta[(c * 32 + qq * 8 + 4 + j) * 128 + colN];
            }
            tsplit8(u0, u1, wbh[ct][c], wbm[ct][c], wbl[ct][c]);
        }
    }

    __syncthreads();

    // ---- phase 1: sf = cat @ W_friend^T  (16 x 128) ----
    float4v sA[2];
#pragma unroll
    for (int ct = 0; ct < 2; ++ct) sA[ct] = (float4v){0.f, 0.f, 0.f, 0.f};
#pragma unroll
    for (int c = 0; c < 8; ++c) {
        const int fo_ = (c * 64 + lane) * 8;
        bf16x8 ah = *(const bf16x8*)&catH[fo_];
        bf16x8 am = *(const bf16x8*)&catM[fo_];
        bf16x8 al = *(const bf16x8*)&catL[fo_];
#pragma unroll
        for (int ct = 0; ct < 2; ++ct) {
            sA[ct] = MFMA16(ah, wfh[ct][c], sA[ct]);
            sA[ct] = MFMA16(ah, wfm[ct][c], sA[ct]);
            sA[ct] = MFMA16(am, wfh[ct][c], sA[ct]);
            sA[ct] = MFMA16(am, wfm[ct][c], sA[ct]);
            sA[ct] = MFMA16(ah, wfl[ct][c], sA[ct]);
            sA[ct] = MFMA16(al, wfh[ct][c], sA[ct]);
        }
    }

    // ---- write sf back to LDS in A-frag layout (triple-split) ----
#pragma unroll
    for (int ct = 0; ct < 2; ++ct) {
        const int col = wv * 32 + ct * 16 + cn;
        const int c2 = col >> 5, s2 = (col >> 3) & 3, j2 = col & 7;
#pragma unroll
        for (int reg = 0; reg < 4; ++reg) {
            const int row = qq * 4 + reg;
            const int sl = (c2 * 64 + row + 16 * s2) * 8 + j2;
            float x = sA[ct][reg];
            __bf16 h = (__bf16)x; float r1 = x - (float)h;
            __bf16 m = (__bf16)r1; float r2 = r1 - (float)m;
            sfH[sl] = h; sfM[sl] = m; sfL[sl] = (__bf16)r2;
        }
    }
    __syncthreads();

    // ---- phase 2: v = sf @ W_beta  (16 x 128) ----
    float4v vA[2];
#pragma unroll
    for (int ct = 0; ct < 2; ++ct) vA[ct] = (float4v){0.f, 0.f, 0.f, 0.f};
#pragma unroll
    for (int c = 0; c < 4; ++c) {
        const int fo_ = (c * 64 + lane) * 8;
        bf16x8 ah = *(const bf16x8*)&sfH[fo_];
        bf16x8 am = *(const bf16x8*)&sfM[fo_];
        bf16x8 al = *(const bf16x8*)&sfL[fo_];
#pragma unroll
        for (int ct = 0; ct < 2; ++ct) {
            vA[ct] = MFMA16(ah, wbh[ct][c], vA[ct]);
            vA[ct] = MFMA16(ah, wbm[ct][c], vA[ct]);
            vA[ct] = MFMA16(am, wbh[ct][c], vA[ct]);
            vA[ct] = MFMA16(am, wbm[ct][c], vA[ct]);
            vA[ct] = MFMA16(ah, wbl[ct][c], vA[ct]);
            vA[ct] = MFMA16(al, wbh[ct][c], vA[ct]);
        }
    }

    // ---- store v ----
#pragma unroll
    for (int ct = 0; ct < 2; ++ct) {
        const int col = wv * 32 + ct * 16 + cn;
#pragma unroll
        for (int reg = 0; reg < 4; ++reg) {
            const int row = qq * 4 + reg;
            vws[(long)(n0 + row) * 128 + col] = vA[ct][reg];
        }
    }
}

// ---------------------------------------------------------------------------
// Kernel 3: attention streaming only — v comes precomputed from proj_kernel.
// ---------------------------------------------------------------------------
__global__ __launch_bounds__(256)
void attn_kernel(const float* __restrict__ common_x,
                 const float* __restrict__ common_time,
                 const int* __restrict__ csm,
                 const float* __restrict__ vws,
                 float* __restrict__ tf)
{
    const int n = blockIdx.x;
    const int tid = threadIdx.x;
    const int wv = tid >> 6, lane = tid & 63;
    __shared__ int lcp[4];
    __shared__ int s_lc;
    __shared__ float wsum[4];

    int mv = csm[(long)n * 256 + tid];
#pragma unroll
    for (int o = 32; o; o >>= 1) mv += __shfl_down(mv, o);
    if (lane == 0) lcp[wv] = mv;
    __syncthreads();
    if (tid == 0) s_lc = lcp[0] + lcp[1] + lcp[2] + lcp[3];
    __syncthreads();

    const int lc = s_lc;
    const int lh = lane & 31, sub = lane >> 5;
    float4v v4 = *(const float4v*)(vws + (long)n * 128 + 4 * lh);
    const float* cxn = common_x + (long)n * 32768 + 4 * lh;
    const float* ctn = common_time + (long)n * 256;
    float acc = 0.f;
#pragma unroll 4
    for (int l0 = wv * 2 + sub; l0 < lc; l0 += 8) {
        float4v x4 = *(const float4v*)(cxn + l0 * 128);
        float p = x4[0] * v4[0] + x4[1] * v4[1] + x4[2] * v4[2] + x4[3] * v4[3];
#pragma unroll
        for (int o = 1; o < 32; o <<= 1) p += __shfl_xor(p, o);
        float contrib = softplusf(p) * __expf(1.0f - ctn[l0] * 1e-6f);
        if (lh == 0) acc += contrib;
    }
    acc += __shfl_xor(acc, 32);
    if (lane == 0) wsum[wv] = acc;
    __syncthreads();
    if (tid == 0) tf[n] = wsum[0] + wsum[1] + wsum[2] + wsum[3];
}

// ---------------------------------------------------------------------------
// Kernel 4: group softmax (over padded zeros, faithful) + weighted sum.
// ---------------------------------------------------------------------------
__global__ __launch_bounds__(128)
void agg_kernel(const float* __restrict__ tf, const float* __restrict__ fo,
                const int* __restrict__ gather_idx, const int* __restrict__ pad_mask,
                float* __restrict__ out)
{
    const int b = blockIdx.x, tid = threadIdx.x;
    __shared__ float tfp[16];
    __shared__ int gidx[16];
    __shared__ float pmf[16];
    if (tid < 16) {
        const int gg = gather_idx[b * 16 + tid];
        const int pp = pad_mask[b * 16 + tid];
        gidx[tid] = gg; pmf[tid] = (float)pp;
        tfp[tid] = pp ? tf[gg] : 0.0f;
    }
    __syncthreads();
    float m = tfp[0];
#pragma unroll
    for (int f = 1; f < 16; ++f) m = fmaxf(m, tfp[f]);
    float e[16]; float s = 0.f;
#pragma unroll
    for (int f = 0; f < 16; ++f) { e[f] = __expf(tfp[f] - m); s += e[f]; }
    const float inv = 1.0f / s;
    float acc = 0.f;
#pragma unroll
    for (int f = 0; f < 16; ++f) {
        if (pmf[f] != 0.0f) {
            const float w = e[f] * inv;
            acc += w * fo[(long)gidx[f] * 128 + tid];
        }
    }
    out[b * 128 + tid] = acc;
}

extern "C" void kernel_launch(void* const* d_in, const int* in_sizes, int n_in,
                              void* d_out, int out_size, void* d_ws, size_t ws_size,
                              hipStream_t stream)
{
    const float* self_x      = (const float*)d_in[0];
    const float* common_x    = (const float*)d_in[1];
    const float* common_time = (const float*)d_in[2];
    const float* friend_x    = (const float*)d_in[3];
    const float* W_ih        = (const float*)d_in[4];
    const float* W_hh        = (const float*)d_in[5];
    const float* b_ih        = (const float*)d_in[6];
    const float* b_hh        = (const float*)d_in[7];
    const float* W_friend    = (const float*)d_in[8];
    const float* W_beta      = (const float*)d_in[9];
    const int* fmask         = (const int*)d_in[10];
    const int* csm           = (const int*)d_in[11];
    const int* uidx          = (const int*)d_in[12];
    const int* gidx          = (const int*)d_in[13];
    const int* pmask         = (const int*)d_in[14];
    float* out = (float*)d_out;

    const int N = in_sizes[12];          // 4352
    const int B = in_sizes[0] / 128;     // 512

    float* fo_ws = (float*)d_ws;                       // [N,128] fp32
    float* tf_ws = fo_ws + (size_t)N * 128;            // [N] fp32
    float* v_ws  = tf_ws + (size_t)N;                  // [N,128] fp32

    gru_kernel<<<(N + 15) / 16, 256, 0, stream>>>(friend_x, W_ih, W_hh, b_ih, b_hh,
                                                  fmask, fo_ws);
    proj_kernel<<<N / 16, 256, 0, stream>>>(self_x, fo_ws, W_friend, W_beta,
                                            uidx, v_ws);
    attn_kernel<<<N, 256, 0, stream>>>(common_x, common_time, csm, v_ws, tf_ws);
    agg_kernel<<<B, 128, 0, stream>>>(tf_ws, fo_ws, gidx, pmask, out);

    (void)n_in; (void)out_size; (void)ws_size;
}

// Round 4
// 909.239 us; speedup vs baseline: 1.1409x; 1.0950x over previous
//
#include <hip/hip_runtime.h>
#include <hip/hip_bf16.h>
#include <hip/hip_fp16.h>

typedef float float4v __attribute__((ext_vector_type(4)));
typedef __bf16 bf16x8 __attribute__((ext_vector_type(8)));
typedef _Float16 halfx8 __attribute__((ext_vector_type(8)));

#define MFMA16(a, b, c)  __builtin_amdgcn_mfma_f32_16x16x32_bf16(a, b, c, 0, 0, 0)
#define MFMA16H(a, b, c) __builtin_amdgcn_mfma_f32_16x16x32_f16(a, b, c, 0, 0, 0)

__device__ __forceinline__ float fsigmoid(float x) {
    return __builtin_amdgcn_rcpf(1.0f + __expf(-x));
}
__device__ __forceinline__ float ftanh_(float x) {
    float e = __expf(2.0f * x);
    return 1.0f - 2.0f * __builtin_amdgcn_rcpf(e + 1.0f);
}
__device__ __forceinline__ float softplusf(float x) {
    return fmaxf(x, 0.0f) + __logf(1.0f + __expf(-fabsf(x)));
}

// ---------------------------------------------------------------------------
// Kernel 1: GRU, fp16 2-term compensated MFMA.
//   product = (a_hi + a_lo) . W_fp16 ; a hi/lo fp16 pair is exact to 2^-22,
//   so the only error is W's fp16 rounding (2^-11 relative, |W|<=0.089).
//   96 MFMAs/step (was 144 with bf16 3-term) -> critical-path pipe floor
//   drops 75 -> 50 us. h-phase / x-phase split retained (epilogue VALU
//   overlaps next-step x MFMAs). Weights live in 192 VGPRs.
// ---------------------------------------------------------------------------
#define STAGE(U0, U1, XHd, XLd) {                                              \
    halfx8 fh, fl;                                                             \
    _Pragma("unroll")                                                          \
    for (int j = 0; j < 4; ++j) {                                              \
        _Float16 h0 = (_Float16)(U0)[j]; fh[j] = h0;                           \
        fl[j] = (_Float16)((U0)[j] - (float)h0);                               \
        _Float16 h1 = (_Float16)(U1)[j]; fh[j + 4] = h1;                       \
        fl[j + 4] = (_Float16)((U1)[j] - (float)h1);                           \
    }                                                                          \
    *(halfx8*)&(XHd)[tid * 8] = fh;                                            \
    *(halfx8*)&(XLd)[tid * 8] = fl;                                            \
}

#define X_PHASE(XHp, XLp)                                                      \
    _Pragma("unroll")                                                          \
    for (int c = 0; c < 4; ++c) {                                              \
        const int fo_ = (c * 64 + lane) * 8;                                   \
        halfx8 xh = *(const halfx8*)&(XHp)[fo_];                               \
        halfx8 xl = *(const halfx8*)&(XLp)[fo_];                               \
        _Pragma("unroll")                                                      \
        for (int ct = 0; ct < 2; ++ct) {                                       \
            nR[ct]  = MFMA16H(xh, wih[0][ct][c], nR[ct]);                      \
            nR[ct]  = MFMA16H(xl, wih[0][ct][c], nR[ct]);                      \
            nZ[ct]  = MFMA16H(xh, wih[1][ct][c], nZ[ct]);                      \
            nZ[ct]  = MFMA16H(xl, wih[1][ct][c], nZ[ct]);                      \
            nIN[ct] = MFMA16H(xh, wih[2][ct][c], nIN[ct]);                     \
            nIN[ct] = MFMA16H(xl, wih[2][ct][c], nIN[ct]);                     \
        }                                                                      \
    }

#define NEXT_INIT()                                                            \
    _Pragma("unroll")                                                          \
    for (int ct = 0; ct < 2; ++ct) {                                           \
        nR[ct]  = (float4v){biasR[ct],  biasR[ct],  biasR[ct],  biasR[ct]};    \
        nZ[ct]  = (float4v){biasZ[ct],  biasZ[ct],  biasZ[ct],  biasZ[ct]};    \
        nIN[ct] = (float4v){biasIN[ct], biasIN[ct], biasIN[ct], biasIN[ct]};   \
    }

__global__ __launch_bounds__(256, 1)
void gru_kernel(const float* __restrict__ friend_x,
                const float* __restrict__ W_ih, const float* __restrict__ W_hh,
                const float* __restrict__ b_ih, const float* __restrict__ b_hh,
                const int* __restrict__ fmask,
                float* __restrict__ friend_out)
{
    __shared__ __align__(16) _Float16 lds[8 * 2048];
    __shared__ int s_lf[16];
    __shared__ int s_n[16];

    const int tid = threadIdx.x;
    const int wv = tid >> 6;
    const int lane = tid & 63;
    const int cn = lane & 15;
    const int qq = lane >> 4;

    _Float16* const XH0 = lds;
    _Float16* const XH1 = lds + 2048;
    _Float16* const XL0 = lds + 2 * 2048;
    _Float16* const XL1 = lds + 3 * 2048;
    _Float16* const HH0 = lds + 4 * 2048;
    _Float16* const HH1 = lds + 5 * 2048;
    _Float16* const HL0 = lds + 6 * 2048;
    _Float16* const HL1 = lds + 7 * 2048;

    if (tid < 16) {
        const int p = blockIdx.x * 16 + tid;
        const int v = p / 68;
        const int j = p - v * 68;
        const int n = (63 - v) + 64 * j;
        s_n[tid] = n;
        const int* mp = fmask + (long)n * 64;
        int s = 0;
        for (int i = 0; i < 64; ++i) s += mp[i];
        s_lf[tid] = s;
    }

    {
        halfx8 z8;
#pragma unroll
        for (int j = 0; j < 8; ++j) z8[j] = (_Float16)0.0f;
        for (int i = tid; i < 4 * 2048 / 8; i += 256) ((halfx8*)HH0)[i] = z8;
    }

    // ---- weights -> registers as single-fp16 B-frags ----
    halfx8 wih[3][2][4], whh[3][2][4];
#pragma unroll
    for (int gate = 0; gate < 3; ++gate)
#pragma unroll
        for (int ct = 0; ct < 2; ++ct) {
            const int row = gate * 128 + wv * 32 + ct * 16 + cn;
#pragma unroll
            for (int c = 0; c < 4; ++c) {
                const float* p = W_ih + row * 128 + c * 32 + qq * 8;
                float4v u0 = *(const float4v*)p;
                float4v u1 = *(const float4v*)(p + 4);
                halfx8 f;
#pragma unroll
                for (int j = 0; j < 4; ++j) {
                    f[j] = (_Float16)u0[j];
                    f[j + 4] = (_Float16)u1[j];
                }
                wih[gate][ct][c] = f;
                const float* q = W_hh + row * 128 + c * 32 + qq * 8;
                float4v v0 = *(const float4v*)q;
                float4v v1 = *(const float4v*)(q + 4);
                halfx8 g;
#pragma unroll
                for (int j = 0; j < 4; ++j) {
                    g[j] = (_Float16)v0[j];
                    g[j + 4] = (_Float16)v1[j];
                }
                whh[gate][ct][c] = g;
            }
        }

    float biasR[2], biasZ[2], biasIN[2], biasHN[2];
#pragma unroll
    for (int ct = 0; ct < 2; ++ct) {
        const int cc = wv * 32 + ct * 16 + cn;
        biasR[ct] = b_ih[cc] + b_hh[cc];
        biasZ[ct] = b_ih[128 + cc] + b_hh[128 + cc];
        biasIN[ct] = b_ih[256 + cc];
        biasHN[ct] = b_hh[256 + cc];
    }

    __syncthreads();

    const int srow = lane & 15;
    const int ss = lane >> 4;
    const float* xp = friend_x + (long)s_n[srow] * 8192 + wv * 32 + ss * 8;

    int lfA[4], nA[4];
#pragma unroll
    for (int r = 0; r < 4; ++r) { lfA[r] = s_lf[qq * 4 + r]; nA[r] = s_n[qq * 4 + r]; }
    int maxlf = 0;
    for (int i = 0; i < 16; ++i) maxlf = (s_lf[i] > maxlf) ? s_lf[i] : maxlf;

    {
        float4v a0 = *(const float4v*)(xp);
        float4v a1 = *(const float4v*)(xp + 4);
        float4v b0 = *(const float4v*)(xp + 128);
        float4v b1 = *(const float4v*)(xp + 132);
        STAGE(a0, a1, XH0, XL0);
        STAGE(b0, b1, XH1, XL1);
    }
    __syncthreads();

    float4v nR[2], nZ[2], nIN[2];
    NEXT_INIT();
    X_PHASE(XH0, XL0);
    __syncthreads();

    float hC[2][4];
#pragma unroll
    for (int ct = 0; ct < 2; ++ct)
#pragma unroll
        for (int r = 0; r < 4; ++r) hC[ct][r] = 0.0f;

    for (int t = 0; t < maxlf; ++t) {
        const int cur = t & 1;
        _Float16* const HHc = cur ? HH1 : HH0;
        _Float16* const HLc = cur ? HL1 : HL0;
        _Float16* const XHr = cur ? XH0 : XH1;
        _Float16* const XLr = cur ? XL0 : XL1;
        _Float16* const XHw = cur ? XH1 : XH0;
        _Float16* const XLw = cur ? XL1 : XL0;
        _Float16* const HHn = cur ? HH0 : HH1;
        _Float16* const HLn = cur ? HL0 : HL1;

        const bool pf2 = (t + 2 < maxlf);
        float4v u0, u1;
        if (pf2) {
            u0 = *(const float4v*)(xp + (t + 2) * 128);
            u1 = *(const float4v*)(xp + (t + 2) * 128 + 4);
        }

        float4v aR[2], aZ[2], aIN[2], aHN[2];
#pragma unroll
        for (int ct = 0; ct < 2; ++ct) {
            aR[ct] = nR[ct]; aZ[ct] = nZ[ct]; aIN[ct] = nIN[ct];
            aHN[ct] = (float4v){biasHN[ct], biasHN[ct], biasHN[ct], biasHN[ct]};
        }

        // ---- h-phase: 48 MFMAs, (h_hi + h_lo) . W_hh ----
#pragma unroll
        for (int c = 0; c < 4; ++c) {
            const int fo_ = (c * 64 + lane) * 8;
            halfx8 hh = *(const halfx8*)&HHc[fo_];
            halfx8 hl = *(const halfx8*)&HLc[fo_];
#pragma unroll
            for (int ct = 0; ct < 2; ++ct) {
                aR[ct]  = MFMA16H(hh, whh[0][ct][c], aR[ct]);
                aR[ct]  = MFMA16H(hl, whh[0][ct][c], aR[ct]);
                aZ[ct]  = MFMA16H(hh, whh[1][ct][c], aZ[ct]);
                aZ[ct]  = MFMA16H(hl, whh[1][ct][c], aZ[ct]);
                aHN[ct] = MFMA16H(hh, whh[2][ct][c], aHN[ct]);
                aHN[ct] = MFMA16H(hl, whh[2][ct][c], aHN[ct]);
            }
        }

        // ---- x-phase for t+1: 48 MFMAs, independent of epilogue regs ----
        const bool hasNext = (t + 1 < maxlf);
        if (hasNext) {
            NEXT_INIT();
            X_PHASE(XHr, XLr);
        }

        if (pf2) {
            STAGE(u0, u1, XHw, XLw);
        }

        // ---- epilogue: gates (fp32) + h update + write h hi/lo ----
#pragma unroll
        for (int ct = 0; ct < 2; ++ct) {
            const int col = wv * 32 + ct * 16 + cn;
            const int c2 = col >> 5, s2 = (col >> 3) & 3, j2 = col & 7;
#pragma unroll
            for (int reg = 0; reg < 4; ++reg) {
                const int row = qq * 4 + reg;
                float r = fsigmoid(aR[ct][reg]);
                float z = fsigmoid(aZ[ct][reg]);
                float nn = ftanh_(aIN[ct][reg] + r * aHN[ct][reg]);
                float h = (1.0f - z) * nn + z * hC[ct][reg];
                hC[ct][reg] = h;
                _Float16 hhi = (_Float16)h;
                _Float16 hlo = (_Float16)(h - (float)hhi);
                const int sl = (c2 * 64 + row + 16 * s2) * 8 + j2;
                HHn[sl] = hhi;
                HLn[sl] = hlo;
                if (t + 1 == lfA[reg])
                    friend_out[(long)nA[reg] * 128 + col] = h;
            }
        }

        __syncthreads();
    }
}

// ---------------------------------------------------------------------------
// Kernel 2: proj — v[n,:] = W_beta^T (W_friend . cat_n) for ALL n once.
// Triple-split bf16 MFMA (fp32-equivalent). Unchanged.
// ---------------------------------------------------------------------------
__device__ __forceinline__ void tsplit8(const float4v u0, const float4v u1,
                                        bf16x8& fh, bf16x8& fm, bf16x8& fl)
{
#pragma unroll
    for (int j = 0; j < 4; ++j) {
        float x0 = u0[j];
        __bf16 h0 = (__bf16)x0; float r0 = x0 - (float)h0;
        __bf16 m0 = (__bf16)r0; float s0 = r0 - (float)m0;
        fh[j] = h0; fm[j] = m0; fl[j] = (__bf16)s0;
        float x1 = u1[j];
        __bf16 h1 = (__bf16)x1; float r1 = x1 - (float)h1;
        __bf16 m1 = (__bf16)r1; float s1 = r1 - (float)m1;
        fh[j + 4] = h1; fm[j + 4] = m1; fl[j + 4] = (__bf16)s1;
    }
}

__global__ __launch_bounds__(256, 1)
void proj_kernel(const float* __restrict__ self_x,
                 const float* __restrict__ friend_out,
                 const float* __restrict__ W_friend,
                 const float* __restrict__ W_beta,
                 const int* __restrict__ user_idx,
                 float* __restrict__ vws)
{
    __shared__ __align__(16) __bf16 catH[4096], catM[4096], catL[4096];
    __shared__ __align__(16) __bf16 sfH[2048], sfM[2048], sfL[2048];

    const int tid = threadIdx.x;
    const int wv = tid >> 6;
    const int lane = tid & 63;
    const int cn = lane & 15;
    const int qq = lane >> 4;
    const int n0 = blockIdx.x * 16;

    {
        const int srow = lane & 15;
        const int ss = lane >> 4;
        const int n_r = n0 + srow;
        const int k = wv * 32 + ss * 8;
        const float* ps = self_x + (long)user_idx[n_r] * 128 + k;
        float4v a0 = *(const float4v*)ps;
        float4v a1 = *(const float4v*)(ps + 4);
        bf16x8 fh, fm, fl;
        tsplit8(a0, a1, fh, fm, fl);
        *(bf16x8*)&catH[tid * 8] = fh;
        *(bf16x8*)&catM[tid * 8] = fm;
        *(bf16x8*)&catL[tid * 8] = fl;
        const float* pf = friend_out + (long)n_r * 128 + k;
        float4v b0 = *(const float4v*)pf;
        float4v b1 = *(const float4v*)(pf + 4);
        tsplit8(b0, b1, fh, fm, fl);
        *(bf16x8*)&catH[(tid + 256) * 8] = fh;
        *(bf16x8*)&catM[(tid + 256) * 8] = fm;
        *(bf16x8*)&catL[(tid + 256) * 8] = fl;
    }

    bf16x8 wfh[2][8], wfm[2][8], wfl[2][8];
#pragma unroll
    for (int ct = 0; ct < 2; ++ct) {
        const int hcol = wv * 32 + ct * 16 + cn;
#pragma unroll
        for (int c = 0; c < 8; ++c) {
            const float* p = W_friend + hcol * 256 + c * 32 + qq * 8;
            float4v u0 = *(const float4v*)p;
            float4v u1 = *(const float4v*)(p + 4);
            tsplit8(u0, u1, wfh[ct][c], wfm[ct][c], wfl[ct][c]);
        }
    }

    bf16x8 wbh[2][4], wbm[2][4], wbl[2][4];
#pragma unroll
    for (int ct = 0; ct < 2; ++ct) {
        const int colN = wv * 32 + ct * 16 + cn;
#pragma unroll
        for (int c = 0; c < 4; ++c) {
            float4v u0, u1;
#pragma unroll
            for (int j = 0; j < 4; ++j) {
                u0[j] = W_beta[(c * 32 + qq * 8 + j) * 128 + colN];
                u1[j] = W_beta[(c * 32 + qq * 8 + 4 + j) * 128 + colN];
            }
            tsplit8(u0, u1, wbh[ct][c], wbm[ct][c], wbl[ct][c]);
        }
    }

    __syncthreads();

    float4v sA[2];
#pragma unroll
    for (int ct = 0; ct < 2; ++ct) sA[ct] = (float4v){0.f, 0.f, 0.f, 0.f};
#pragma unroll
    for (int c = 0; c < 8; ++c) {
        const int fo_ = (c * 64 + lane) * 8;
        bf16x8 ah = *(const bf16x8*)&catH[fo_];
        bf16x8 am = *(const bf16x8*)&catM[fo_];
        bf16x8 al = *(const bf16x8*)&catL[fo_];
#pragma unroll
        for (int ct = 0; ct < 2; ++ct) {
            sA[ct] = MFMA16(ah, wfh[ct][c], sA[ct]);
            sA[ct] = MFMA16(ah, wfm[ct][c], sA[ct]);
            sA[ct] = MFMA16(am, wfh[ct][c], sA[ct]);
            sA[ct] = MFMA16(am, wfm[ct][c], sA[ct]);
            sA[ct] = MFMA16(ah, wfl[ct][c], sA[ct]);
            sA[ct] = MFMA16(al, wfh[ct][c], sA[ct]);
        }
    }

#pragma unroll
    for (int ct = 0; ct < 2; ++ct) {
        const int col = wv * 32 + ct * 16 + cn;
        const int c2 = col >> 5, s2 = (col >> 3) & 3, j2 = col & 7;
#pragma unroll
        for (int reg = 0; reg < 4; ++reg) {
            const int row = qq * 4 + reg;
            const int sl = (c2 * 64 + row + 16 * s2) * 8 + j2;
            float x = sA[ct][reg];
            __bf16 h = (__bf16)x; float r1 = x - (float)h;
            __bf16 m = (__bf16)r1; float r2 = r1 - (float)m;
            sfH[sl] = h; sfM[sl] = m; sfL[sl] = (__bf16)r2;
        }
    }
    __syncthreads();

    float4v vA[2];
#pragma unroll
    for (int ct = 0; ct < 2; ++ct) vA[ct] = (float4v){0.f, 0.f, 0.f, 0.f};
#pragma unroll
    for (int c = 0; c < 4; ++c) {
        const int fo_ = (c * 64 + lane) * 8;
        bf16x8 ah = *(const bf16x8*)&sfH[fo_];
        bf16x8 am = *(const bf16x8*)&sfM[fo_];
        bf16x8 al = *(const bf16x8*)&sfL[fo_];
#pragma unroll
        for (int ct = 0; ct < 2; ++ct) {
            vA[ct] = MFMA16(ah, wbh[ct][c], vA[ct]);
            vA[ct] = MFMA16(ah, wbm[ct][c], vA[ct]);
            vA[ct] = MFMA16(am, wbh[ct][c], vA[ct]);
            vA[ct] = MFMA16(am, wbm[ct][c], vA[ct]);
            vA[ct] = MFMA16(ah, wbl[ct][c], vA[ct]);
            vA[ct] = MFMA16(al, wbh[ct][c], vA[ct]);
        }
    }

#pragma unroll
    for (int ct = 0; ct < 2; ++ct) {
        const int col = wv * 32 + ct * 16 + cn;
#pragma unroll
        for (int reg = 0; reg < 4; ++reg) {
            const int row = qq * 4 + reg;
            vws[(long)(n0 + row) * 128 + col] = vA[ct][reg];
        }
    }
}

// ---------------------------------------------------------------------------
// Kernel 3: attention streaming (unchanged).
// ---------------------------------------------------------------------------
__global__ __launch_bounds__(256)
void attn_kernel(const float* __restrict__ common_x,
                 const float* __restrict__ common_time,
                 const int* __restrict__ csm,
                 const float* __restrict__ vws,
                 float* __restrict__ tf)
{
    const int n = blockIdx.x;
    const int tid = threadIdx.x;
    const int wv = tid >> 6, lane = tid & 63;
    __shared__ int lcp[4];
    __shared__ int s_lc;
    __shared__ float wsum[4];

    int mv = csm[(long)n * 256 + tid];
#pragma unroll
    for (int o = 32; o; o >>= 1) mv += __shfl_down(mv, o);
    if (lane == 0) lcp[wv] = mv;
    __syncthreads();
    if (tid == 0) s_lc = lcp[0] + lcp[1] + lcp[2] + lcp[3];
    __syncthreads();

    const int lc = s_lc;
    const int lh = lane & 31, sub = lane >> 5;
    float4v v4 = *(const float4v*)(vws + (long)n * 128 + 4 * lh);
    const float* cxn = common_x + (long)n * 32768 + 4 * lh;
    const float* ctn = common_time + (long)n * 256;
    float acc = 0.f;
#pragma unroll 4
    for (int l0 = wv * 2 + sub; l0 < lc; l0 += 8) {
        float4v x4 = *(const float4v*)(cxn + l0 * 128);
        float p = x4[0] * v4[0] + x4[1] * v4[1] + x4[2] * v4[2] + x4[3] * v4[3];
#pragma unroll
        for (int o = 1; o < 32; o <<= 1) p += __shfl_xor(p, o);
        float contrib = softplusf(p) * __expf(1.0f - ctn[l0] * 1e-6f);
        if (lh == 0) acc += contrib;
    }
    acc += __shfl_xor(acc, 32);
    if (lane == 0) wsum[wv] = acc;
    __syncthreads();
    if (tid == 0) tf[n] = wsum[0] + wsum[1] + wsum[2] + wsum[3];
}

// ---------------------------------------------------------------------------
// Kernel 4: group softmax + weighted sum (unchanged).
// ---------------------------------------------------------------------------
__global__ __launch_bounds__(128)
void agg_kernel(const float* __restrict__ tf, const float* __restrict__ fo,
                const int* __restrict__ gather_idx, const int* __restrict__ pad_mask,
                float* __restrict__ out)
{
    const int b = blockIdx.x, tid = threadIdx.x;
    __shared__ float tfp[16];
    __shared__ int gidx[16];
    __shared__ float pmf[16];
    if (tid < 16) {
        const int gg = gather_idx[b * 16 + tid];
        const int pp = pad_mask[b * 16 + tid];
        gidx[tid] = gg; pmf[tid] = (float)pp;
        tfp[tid] = pp ? tf[gg] : 0.0f;
    }
    __syncthreads();
    float m = tfp[0];
#pragma unroll
    for (int f = 1; f < 16; ++f) m = fmaxf(m, tfp[f]);
    float e[16]; float s = 0.f;
#pragma unroll
    for (int f = 0; f < 16; ++f) { e[f] = __expf(tfp[f] - m); s += e[f]; }
    const float inv = 1.0f / s;
    float acc = 0.f;
#pragma unroll
    for (int f = 0; f < 16; ++f) {
        if (pmf[f] != 0.0f) {
            const float w = e[f] * inv;
            acc += w * fo[(long)gidx[f] * 128 + tid];
        }
    }
    out[b * 128 + tid] = acc;
}

extern "C" void kernel_launch(void* const* d_in, const int* in_sizes, int n_in,
                              void* d_out, int out_size, void* d_ws, size_t ws_size,
                              hipStream_t stream)
{
    const float* self_x      = (const float*)d_in[0];
    const float* common_x    = (const float*)d_in[1];
    const float* common_time = (const float*)d_in[2];
    const float* friend_x    = (const float*)d_in[3];
    const float* W_ih        = (const float*)d_in[4];
    const float* W_hh        = (const float*)d_in[5];
    const float* b_ih        = (const float*)d_in[6];
    const float* b_hh        = (const float*)d_in[7];
    const float* W_friend    = (const float*)d_in[8];
    const float* W_beta      = (const float*)d_in[9];
    const int* fmask         = (const int*)d_in[10];
    const int* csm           = (const int*)d_in[11];
    const int* uidx          = (const int*)d_in[12];
    const int* gidx          = (const int*)d_in[13];
    const int* pmask         = (const int*)d_in[14];
    float* out = (float*)d_out;

    const int N = in_sizes[12];          // 4352
    const int B = in_sizes[0] / 128;     // 512

    float* fo_ws = (float*)d_ws;                       // [N,128] fp32
    float* tf_ws = fo_ws + (size_t)N * 128;            // [N] fp32
    float* v_ws  = tf_ws + (size_t)N;                  // [N,128] fp32

    gru_kernel<<<(N + 15) / 16, 256, 0, stream>>>(friend_x, W_ih, W_hh, b_ih, b_hh,
                                                  fmask, fo_ws);
    proj_kernel<<<N / 16, 256, 0, stream>>>(self_x, fo_ws, W_friend, W_beta,
                                            uidx, v_ws);
    attn_kernel<<<N, 256, 0, stream>>>(common_x, common_time, csm, v_ws, tf_ws);
    agg_kernel<<<B, 128, 0, stream>>>(tf_ws, fo_ws, gidx, pmask, out);

    (void)n_in; (void)out_size; (void)ws_size;
}